// Round 1
// 845.243 us; speedup vs baseline: 1.2443x; 1.2443x over previous
//
#include <hip/hip_runtime.h>
#include <math.h>

#define B_ 8
#define S_ 32
#define D_ 256
#define N_ 256
#define K_ 51
#define V_ 50257

__device__ __forceinline__ float dot4f(float4 a, float4 b){
  return a.x*b.x + a.y*b.y + a.z*b.z + a.w*b.w;
}
__device__ __forceinline__ float gelu_exact(float x){
  return 0.5f * x * (1.0f + erff(x * 0.70710678118654752440f));
}
__device__ __forceinline__ float sigmoidf_(float x){
  return 1.0f / (1.0f + expf(-x));
}

// K1: xt[t*B+b][d] = embed[ids[b,t]][d] + pos_embed[t][d]
__global__ __launch_bounds__(256) void k_embed(const int* __restrict__ ids,
    const float* __restrict__ embed, const float* __restrict__ pose,
    float* __restrict__ xt)
{
  int bx = blockIdx.x;            // t*8 + b
  int t = bx >> 3, b = bx & 7;
  int d = threadIdx.x;
  int id = ids[b * S_ + t];
  xt[(size_t)bx * D_ + d] = embed[(size_t)id * D_ + d] + pose[(size_t)t * D_ + d];
}

// K2: scores[t*B+b][n] = dot(xt[t,b], router_W[n]) + router_b[n]
__global__ __launch_bounds__(256) void k_router(const float* __restrict__ xt,
    const float* __restrict__ rW, const float* __restrict__ rb,
    float* __restrict__ scores)
{
  int bx = blockIdx.x;            // t*8 + b
  int tid = threadIdx.x;
  __shared__ float4 xs4[64];
  if (tid < 64) xs4[tid] = ((const float4*)(xt + (size_t)bx * D_))[tid];
  __syncthreads();
  float acc = rb[tid];
  const float4* wp = (const float4*)(rW + (size_t)tid * D_);
  for (int d4 = 0; d4 < 64; d4++){
    float4 w = wp[d4]; float4 x = xs4[d4];
    acc += dot4f(w, x);
  }
  scores[(size_t)bx * N_ + tid] = acc;
}

// K3: per (t,b): full bitonic sort desc (tie: low idx first), softmax over top-K,
// and for b==0 build active/member/pos for step t.
__global__ __launch_bounds__(256) void k_topk(const float* __restrict__ scores,
    float* __restrict__ wbuf, int* __restrict__ active,
    int* __restrict__ member, int* __restrict__ pos)
{
  int bx = blockIdx.x;            // t*8 + b
  int t = bx >> 3, b = bx & 7;
  int tid = threadIdx.x;
  __shared__ float sv[256];
  __shared__ int   si[256];
  __shared__ float ex[K_];
  __shared__ float exsum;
  sv[tid] = scores[(size_t)bx * N_ + tid];
  si[tid] = tid;
  for (int kk = 2; kk <= 256; kk <<= 1){
    for (int j = kk >> 1; j > 0; j >>= 1){
      __syncthreads();
      int ixj = tid ^ j;
      if (ixj > tid){
        float va = sv[tid], vb = sv[ixj];
        int   ia = si[tid], ib = si[ixj];
        bool before = (va > vb) || (va == vb && ia < ib);
        bool up = ((tid & kk) == 0);
        if (up != before){
          sv[tid] = vb; sv[ixj] = va;
          si[tid] = ib; si[ixj] = ia;
        }
      }
    }
  }
  __syncthreads();
  float vmax = sv[0];
  if (tid < K_) ex[tid] = expf(sv[tid] - vmax);
  __syncthreads();
  if (tid == 0){
    float s = 0.0f;
    for (int k = 0; k < K_; k++) s += ex[k];
    exsum = s;
  }
  __syncthreads();
  if (tid < K_) wbuf[(size_t)bx * K_ + tid] = ex[tid] / exsum;
  if (b == 0){
    member[t * N_ + tid] = 0;
    pos[t * N_ + tid] = 0;
    __syncthreads();               // uniform branch within block
    if (tid < K_){
      int nn = si[tid];
      active[t * K_ + tid] = nn;
      member[t * N_ + nn] = 1;
      pos[t * N_ + nn] = tid;
    }
  }
}

// K3b: compact active (e,t) pairs into a worklist.
__global__ __launch_bounds__(256) void k_compact(const int* __restrict__ esrc,
    const int* __restrict__ edst, const int* __restrict__ member,
    int E, int* __restrict__ count, unsigned int* __restrict__ items)
{
  int idx = blockIdx.x * 256 + threadIdx.x;
  if (idx >= E * S_) return;
  int e = idx % E, t = idx / E;
  int src = esrc[e], dst = edst[e];
  if (member[t * N_ + src] && member[t * N_ + dst]){
    int slot = atomicAdd(count, 1);
    items[slot] = ((unsigned int)t << 16) | (unsigned int)e;
  }
}

// K4: hop0. block (k, t), 256 threads; thread owns row o=tid.
// states[t,k,b,o] = gelu(h)*g[b]*w[b,k]
__global__ __launch_bounds__(256) void k_hop0(const float* __restrict__ xt,
    const float* __restrict__ fcW, const float* __restrict__ fcB,
    const float* __restrict__ gateW, const float* __restrict__ gateB,
    const float* __restrict__ wbuf, const int* __restrict__ active,
    float* __restrict__ states)
{
  int k = blockIdx.x, t = blockIdx.y;
  int tid = threadIdx.x;
  __shared__ float xs[B_ * D_];
  __shared__ float gl[B_];
  __shared__ float wl[B_];
  int n = active[t * K_ + k];
  float4* xs4 = (float4*)xs;
  const float4* xt4 = (const float4*)(xt + (size_t)t * B_ * D_);
  #pragma unroll
  for (int i = 0; i < 2; i++) xs4[tid + i * 256] = xt4[tid + i * 256];
  if (tid < B_) wl[tid] = wbuf[(size_t)(t * B_ + tid) * K_ + k];
  __syncthreads();
  // gate: wave w computes b = 2w, 2w+1
  {
    int wave = tid >> 6, lane = tid & 63;
    float4 gw = ((const float4*)(gateW + (size_t)n * D_))[lane];
    float a0 = dot4f(gw, xs4[(wave * 2 + 0) * 64 + lane]);
    float a1 = dot4f(gw, xs4[(wave * 2 + 1) * 64 + lane]);
    for (int s2 = 1; s2 < 64; s2 <<= 1){
      a0 += __shfl_xor(a0, s2, 64);
      a1 += __shfl_xor(a1, s2, 64);
    }
    if (lane == 0){
      float gb = gateB[n];
      gl[wave * 2 + 0] = sigmoidf_(a0 + gb);
      gl[wave * 2 + 1] = sigmoidf_(a1 + gb);
    }
  }
  __syncthreads();
  // main: h[b][o] for o = tid
  float acc[B_] = {0,0,0,0,0,0,0,0};
  const float4* wp = (const float4*)(fcW + (size_t)n * D_ * D_ + (size_t)tid * D_);
  for (int d4 = 0; d4 < 64; d4++){
    float4 w = wp[d4];
    #pragma unroll
    for (int b = 0; b < B_; b++) acc[b] += dot4f(w, xs4[b * 64 + d4]);
  }
  float fb = fcB[(size_t)n * D_ + tid];
  #pragma unroll
  for (int b = 0; b < B_; b++){
    float s = gelu_exact(acc[b] + fb) * gl[b] * wl[b];
    states[((size_t)(t * K_ + k) * B_ + b) * D_ + tid] = s;
  }
}

// K5: edge pass over compacted worklist. 256 threads, grid-stride over items.
__global__ __launch_bounds__(256) void k_edge2(const float* __restrict__ states,
    const float* __restrict__ connW, const float* __restrict__ fcW,
    const float* __restrict__ fcB, const float* __restrict__ gateW,
    const float* __restrict__ gateB, const int* __restrict__ esrc,
    const int* __restrict__ edst, const int* __restrict__ pos,
    const int* __restrict__ count, const unsigned int* __restrict__ items,
    float* __restrict__ nxt)
{
  __shared__ float xs[B_ * D_];
  __shared__ float sg[B_ * D_];
  __shared__ float gl[B_];
  int n_items = *count;
  int tid = threadIdx.x;
  float4* xs4 = (float4*)xs;
  float4* sg4 = (float4*)sg;
  for (int it = blockIdx.x; it < n_items; it += gridDim.x){
    unsigned int pk = items[it];
    int t = (int)(pk >> 16), e = (int)(pk & 0xFFFFu);
    int src = esrc[e], dst = edst[e];
    int ks = pos[t * N_ + src], kd = pos[t * N_ + dst];
    const float4* st4 = (const float4*)(states + (size_t)(t * K_ + ks) * B_ * D_);
    #pragma unroll
    for (int i = 0; i < 2; i++) xs4[tid + i * 256] = st4[tid + i * 256];
    __syncthreads();
    // GEMM1: sig[b][o] for o = tid
    {
      float acc[B_] = {0,0,0,0,0,0,0,0};
      const float4* wp = (const float4*)(connW + (size_t)e * D_ * D_ + (size_t)tid * D_);
      for (int d4 = 0; d4 < 64; d4++){
        float4 w = wp[d4];
        #pragma unroll
        for (int b = 0; b < B_; b++) acc[b] += dot4f(w, xs4[b * 64 + d4]);
      }
      #pragma unroll
      for (int b = 0; b < B_; b++) sg[b * D_ + tid] = acc[b];
    }
    __syncthreads();
    // gate gg[b] = sigmoid(dot(sig[b], gateW[dst]) + gateB[dst])
    {
      int wave = tid >> 6, lane = tid & 63;
      float4 gw = ((const float4*)(gateW + (size_t)dst * D_))[lane];
      float a0 = dot4f(gw, sg4[(wave * 2 + 0) * 64 + lane]);
      float a1 = dot4f(gw, sg4[(wave * 2 + 1) * 64 + lane]);
      for (int s2 = 1; s2 < 64; s2 <<= 1){
        a0 += __shfl_xor(a0, s2, 64);
        a1 += __shfl_xor(a1, s2, 64);
      }
      if (lane == 0){
        float gb = gateB[dst];
        gl[wave * 2 + 0] = sigmoidf_(a0 + gb);
        gl[wave * 2 + 1] = sigmoidf_(a1 + gb);
      }
    }
    __syncthreads();
    // GEMM2: hh[b][o] for o = tid; act -> atomic into nxt[t,kd]
    {
      float acc[B_] = {0,0,0,0,0,0,0,0};
      const float4* wp = (const float4*)(fcW + (size_t)dst * D_ * D_ + (size_t)tid * D_);
      for (int d4 = 0; d4 < 64; d4++){
        float4 w = wp[d4];
        #pragma unroll
        for (int b = 0; b < B_; b++) acc[b] += dot4f(w, sg4[b * 64 + d4]);
      }
      float fb = fcB[(size_t)dst * D_ + tid];
      float* nx = nxt + (size_t)(t * K_ + kd) * B_ * D_;
      #pragma unroll
      for (int b = 0; b < B_; b++){
        float a = gelu_exact(acc[b] + fb) * gl[b];
        atomicAdd(&nx[b * D_ + tid], a);
      }
    }
    __syncthreads();   // protect xs/sg before next iteration overwrites
  }
}

// K6: combine (mean over k of states+0.5*nxt) + LayerNorm -> normed[row=b*S+t][d]
__global__ __launch_bounds__(256) void k_ln(const float* __restrict__ states,
    const float* __restrict__ nxt, const float* __restrict__ lng,
    const float* __restrict__ lnb, float* __restrict__ normed)
{
  int row = blockIdx.x;           // b*S + t
  int b = row >> 5, t = row & 31;
  int d = threadIdx.x;
  float v = 0.0f;
  for (int k = 0; k < K_; k++){
    size_t idx = ((size_t)(t * K_ + k) * B_ + b) * D_ + d;
    v += states[idx] + 0.5f * nxt[idx];
  }
  v /= 51.0f;
  __shared__ float red[256];
  red[d] = v; __syncthreads();
  for (int s = 128; s > 0; s >>= 1){ if (d < s) red[d] += red[d + s]; __syncthreads(); }
  float mu = red[0] * (1.0f / 256.0f);
  __syncthreads();
  float c = v - mu;
  red[d] = c * c; __syncthreads();
  for (int s = 128; s > 0; s >>= 1){ if (d < s) red[d] += red[d + s]; __syncthreads(); }
  float var = red[0] * (1.0f / 256.0f);
  normed[(size_t)row * D_ + d] = c * rsqrtf(var + 1e-5f) * lng[d] + lnb[d];
}

// K7 (rewritten): tiled FP32 GEMM. out[r][v] = dot(normed[r], outW[v]) + outB[v].
// Block tile: 64 rows x 128 cols, K-chunks of 64 staged TRANSPOSED into LDS.
//   Ws[k][c] pad-132 (16B-aligned rows, conflict-free contiguous b128 reads)
//   Xs[k][r] pad-68  (broadcast b128 reads)
// 256 threads; thread (rg=tid>>5, cg=tid&31) owns 8 rows x 4 cols = 32 accs.
// grid = (ceil(V/128)=393, 4) = 1572 blocks; 50 KiB LDS -> 3 blocks/CU.
__global__ __launch_bounds__(256) void k_logits(const float* __restrict__ normed,
    const float* __restrict__ outW, const float* __restrict__ outB,
    float* __restrict__ out)
{
  __shared__ float Ws[64][132];   // 33792 B
  __shared__ float Xs[64][68];    // 17408 B
  int tid = threadIdx.x;
  int vbase = blockIdx.x * 128;
  int rbase = blockIdx.y * 64;
  int cg = tid & 31;              // 4 cols: vbase + cg*4 + j
  int rg = tid >> 5;              // 8 rows: rbase + rg*8 + i
  float acc[8][4];
  #pragma unroll
  for (int i = 0; i < 8; i++)
    #pragma unroll
    for (int j = 0; j < 4; j++) acc[i][j] = 0.0f;

  for (int kb = 0; kb < 4; kb++){           // k-chunk = [kb*64, kb*64+64)
    if (kb) __syncthreads();                // protect prev-chunk reads
    // stage W chunk transposed: 128 rows(v) x 16 float4(k) = 2048 quads, 8/thread
    #pragma unroll
    for (int i = 0; i < 8; i++){
      int idx = tid + i * 256;
      int v = idx >> 4, kq = idx & 15;
      int gv = vbase + v;
      float4 w = make_float4(0.0f, 0.0f, 0.0f, 0.0f);
      if (gv < V_) w = ((const float4*)(outW + (size_t)gv * D_))[kb * 16 + kq];
      Ws[kq * 4 + 0][v] = w.x;
      Ws[kq * 4 + 1][v] = w.y;
      Ws[kq * 4 + 2][v] = w.z;
      Ws[kq * 4 + 3][v] = w.w;
    }
    // stage X chunk transposed: 64 rows x 16 quads = 1024 quads, 4/thread
    #pragma unroll
    for (int i = 0; i < 4; i++){
      int idx = tid + i * 256;
      int r = idx >> 4, kq = idx & 15;
      float4 x = ((const float4*)(normed + (size_t)(rbase + r) * D_))[kb * 16 + kq];
      Xs[kq * 4 + 0][r] = x.x;
      Xs[kq * 4 + 1][r] = x.y;
      Xs[kq * 4 + 2][r] = x.z;
      Xs[kq * 4 + 3][r] = x.w;
    }
    __syncthreads();
    // outer-product inner loop: per k, 3 ds_read_b128 + 32 v_fma
    #pragma unroll 4
    for (int k = 0; k < 64; k++){
      float4 wv = *(const float4*)&Ws[k][cg * 4];
      float4 x0 = *(const float4*)&Xs[k][rg * 8];
      float4 x1 = *(const float4*)&Xs[k][rg * 8 + 4];
      float xr[8] = {x0.x, x0.y, x0.z, x0.w, x1.x, x1.y, x1.z, x1.w};
      float wc[4] = {wv.x, wv.y, wv.z, wv.w};
      #pragma unroll
      for (int i = 0; i < 8; i++)
        #pragma unroll
        for (int j = 0; j < 4; j++)
          acc[i][j] = fmaf(xr[i], wc[j], acc[i][j]);
    }
  }
  // epilogue: scalar stores (V odd -> no aligned vector stores)
  #pragma unroll
  for (int j = 0; j < 4; j++){
    int gc = vbase + cg * 4 + j;
    if (gc < V_){
      float ob = outB[gc];
      #pragma unroll
      for (int i = 0; i < 8; i++)
        out[(size_t)(rbase + rg * 8 + i) * V_ + gc] = acc[i][j] + ob;
    }
  }
}

extern "C" void kernel_launch(void* const* d_in, const int* in_sizes, int n_in,
                              void* d_out, int out_size, void* d_ws, size_t ws_size,
                              hipStream_t stream)
{
  const int*   ids    = (const int*)d_in[0];
  const float* embed  = (const float*)d_in[1];
  const float* pose   = (const float*)d_in[2];
  const float* rW     = (const float*)d_in[3];
  const float* rb     = (const float*)d_in[4];
  const float* fcW    = (const float*)d_in[5];
  const float* fcB    = (const float*)d_in[6];
  const float* gateW  = (const float*)d_in[7];
  const float* gateB  = (const float*)d_in[8];
  const float* connW  = (const float*)d_in[9];
  const float* lng    = (const float*)d_in[10];
  const float* lnb    = (const float*)d_in[11];
  const float* outW   = (const float*)d_in[12];
  const float* outB   = (const float*)d_in[13];
  const int*   esrc   = (const int*)d_in[14];
  const int*   edst   = (const int*)d_in[15];
  int E = in_sizes[14];
  float* out = (float*)d_out;

  char* ws = (char*)d_ws;
  float* xt     = (float*)(ws + 0);          // 256 KB
  float* scores = (float*)(ws + 262144);     // 256 KB (dead after k_topk)
  // alias worklist into the dead scores region:
  unsigned int* items = (unsigned int*)(ws + 262144);   // E*S*4 fits in 256KB
  float* wbuf   = (float*)(ws + 524288);     // 52 KB
  int*   active = (int*)  (ws + 589824);     // 6.5 KB
  int*   count  = (int*)  (ws + 596992);     // 4 B (slack before member)
  int*   member = (int*)  (ws + 598016);     // 32 KB
  int*   pos    = (int*)  (ws + 630784);     // 32 KB
  float* states = (float*)(ws + 663552);     // 13.37 MB
  float* nxt    = (float*)(ws + 14032896);   // 13.37 MB
  float* normed = (float*)(ws + 27402240);   // 256 KB

  hipMemsetAsync(nxt, 0, (size_t)3342336 * 4, stream);

  k_embed  <<<dim3(S_ * B_), 256, 0, stream>>>(ids, embed, pose, xt);
  k_router <<<dim3(S_ * B_), 256, 0, stream>>>(xt, rW, rb, scores);
  k_topk   <<<dim3(S_ * B_), 256, 0, stream>>>(scores, wbuf, active, member, pos);
  hipMemsetAsync(count, 0, 4, stream);       // after k_topk: scores region now dead
  k_compact<<<dim3((E * S_ + 255) / 256), 256, 0, stream>>>(esrc, edst, member, E, count, items);
  k_hop0   <<<dim3(K_, S_), 256, 0, stream>>>(xt, fcW, fcB, gateW, gateB, wbuf, active, states);
  k_edge2  <<<dim3(1280), 256, 0, stream>>>(states, connW, fcW, fcB, gateW, gateB,
                                            esrc, edst, pos, count, items, nxt);
  k_ln     <<<dim3(B_ * S_), 256, 0, stream>>>(states, nxt, lng, lnb, normed);
  k_logits <<<dim3((V_ + 127) / 128, 4), 256, 0, stream>>>(normed, outW, outB, out);
}

// Round 2
// 795.781 us; speedup vs baseline: 1.3217x; 1.0622x over previous
//
#include <hip/hip_runtime.h>
#include <math.h>

#define B_ 8
#define S_ 32
#define D_ 256
#define N_ 256
#define K_ 51
#define V_ 50257

__device__ __forceinline__ float dot4f(float4 a, float4 b){
  return a.x*b.x + a.y*b.y + a.z*b.z + a.w*b.w;
}
__device__ __forceinline__ float gelu_exact(float x){
  return 0.5f * x * (1.0f + erff(x * 0.70710678118654752440f));
}
__device__ __forceinline__ float sigmoidf_(float x){
  return 1.0f / (1.0f + expf(-x));
}

// K1: xt[t*B+b][d] = embed[ids[b,t]][d] + pos_embed[t][d]
__global__ __launch_bounds__(256) void k_embed(const int* __restrict__ ids,
    const float* __restrict__ embed, const float* __restrict__ pose,
    float* __restrict__ xt)
{
  int bx = blockIdx.x;            // t*8 + b
  int t = bx >> 3, b = bx & 7;
  int d = threadIdx.x;
  int id = ids[b * S_ + t];
  xt[(size_t)bx * D_ + d] = embed[(size_t)id * D_ + d] + pose[(size_t)t * D_ + d];
}

// K2: scores[t*B+b][n] = dot(xt[t,b], router_W[n]) + router_b[n]
__global__ __launch_bounds__(256) void k_router(const float* __restrict__ xt,
    const float* __restrict__ rW, const float* __restrict__ rb,
    float* __restrict__ scores)
{
  int bx = blockIdx.x;            // t*8 + b
  int tid = threadIdx.x;
  __shared__ float4 xs4[64];
  if (tid < 64) xs4[tid] = ((const float4*)(xt + (size_t)bx * D_))[tid];
  __syncthreads();
  float acc = rb[tid];
  const float4* wp = (const float4*)(rW + (size_t)tid * D_);
  for (int d4 = 0; d4 < 64; d4++){
    float4 w = wp[d4]; float4 x = xs4[d4];
    acc += dot4f(w, x);
  }
  scores[(size_t)bx * N_ + tid] = acc;
}

// K3: per (t,b): full bitonic sort desc (tie: low idx first), softmax over top-K,
// and for b==0 build active/member/pos for step t.
__global__ __launch_bounds__(256) void k_topk(const float* __restrict__ scores,
    float* __restrict__ wbuf, int* __restrict__ active,
    int* __restrict__ member, int* __restrict__ pos)
{
  int bx = blockIdx.x;            // t*8 + b
  int t = bx >> 3, b = bx & 7;
  int tid = threadIdx.x;
  __shared__ float sv[256];
  __shared__ int   si[256];
  __shared__ float ex[K_];
  __shared__ float exsum;
  sv[tid] = scores[(size_t)bx * N_ + tid];
  si[tid] = tid;
  for (int kk = 2; kk <= 256; kk <<= 1){
    for (int j = kk >> 1; j > 0; j >>= 1){
      __syncthreads();
      int ixj = tid ^ j;
      if (ixj > tid){
        float va = sv[tid], vb = sv[ixj];
        int   ia = si[tid], ib = si[ixj];
        bool before = (va > vb) || (va == vb && ia < ib);
        bool up = ((tid & kk) == 0);
        if (up != before){
          sv[tid] = vb; sv[ixj] = va;
          si[tid] = ib; si[ixj] = ia;
        }
      }
    }
  }
  __syncthreads();
  float vmax = sv[0];
  if (tid < K_) ex[tid] = expf(sv[tid] - vmax);
  __syncthreads();
  if (tid == 0){
    float s = 0.0f;
    for (int k = 0; k < K_; k++) s += ex[k];
    exsum = s;
  }
  __syncthreads();
  if (tid < K_) wbuf[(size_t)bx * K_ + tid] = ex[tid] / exsum;
  if (b == 0){
    member[t * N_ + tid] = 0;
    pos[t * N_ + tid] = 0;
    __syncthreads();               // uniform branch within block
    if (tid < K_){
      int nn = si[tid];
      active[t * K_ + tid] = nn;
      member[t * N_ + nn] = 1;
      pos[t * N_ + nn] = tid;
    }
  }
}

// K3b (new): thread-per-edge. Build 32-bit t-mask of steps where both endpoints
// are active, then emit packed chunks of up to 2 t's: e | t0<<16 | t1<<24
// (t1 == 0xFF means single-t chunk). connW[e] and fcW[edst[e]] are then
// streamed once per CHUNK instead of once per (t,e) item.
__global__ __launch_bounds__(256) void k_chunks(const int* __restrict__ esrc,
    const int* __restrict__ edst, const int* __restrict__ member,
    int E, int* __restrict__ ccount, unsigned int* __restrict__ chunks)
{
  int e = blockIdx.x * 256 + threadIdx.x;
  if (e >= E) return;
  int src = esrc[e], dst = edst[e];
  unsigned int mask = 0;
  for (int t = 0; t < S_; t++)
    if (member[t * N_ + src] && member[t * N_ + dst]) mask |= (1u << t);
  while (mask){
    int t0 = __ffs(mask) - 1; mask &= mask - 1;
    unsigned int t1 = 0xFFu;
    if (mask){ t1 = (unsigned int)(__ffs(mask) - 1); mask &= mask - 1; }
    int ci = atomicAdd(ccount, 1);
    chunks[ci] = (unsigned int)e | ((unsigned int)t0 << 16) | (t1 << 24);
  }
}

// K4: hop0. block (k, t), 256 threads; thread owns row o=tid.
// states[t,k,b,o] = gelu(h)*g[b]*w[b,k]
__global__ __launch_bounds__(256) void k_hop0(const float* __restrict__ xt,
    const float* __restrict__ fcW, const float* __restrict__ fcB,
    const float* __restrict__ gateW, const float* __restrict__ gateB,
    const float* __restrict__ wbuf, const int* __restrict__ active,
    float* __restrict__ states)
{
  int k = blockIdx.x, t = blockIdx.y;
  int tid = threadIdx.x;
  __shared__ float xs[B_ * D_];
  __shared__ float gl[B_];
  __shared__ float wl[B_];
  int n = active[t * K_ + k];
  float4* xs4 = (float4*)xs;
  const float4* xt4 = (const float4*)(xt + (size_t)t * B_ * D_);
  #pragma unroll
  for (int i = 0; i < 2; i++) xs4[tid + i * 256] = xt4[tid + i * 256];
  if (tid < B_) wl[tid] = wbuf[(size_t)(t * B_ + tid) * K_ + k];
  __syncthreads();
  // gate: wave w computes b = 2w, 2w+1
  {
    int wave = tid >> 6, lane = tid & 63;
    float4 gw = ((const float4*)(gateW + (size_t)n * D_))[lane];
    float a0 = dot4f(gw, xs4[(wave * 2 + 0) * 64 + lane]);
    float a1 = dot4f(gw, xs4[(wave * 2 + 1) * 64 + lane]);
    for (int s2 = 1; s2 < 64; s2 <<= 1){
      a0 += __shfl_xor(a0, s2, 64);
      a1 += __shfl_xor(a1, s2, 64);
    }
    if (lane == 0){
      float gb = gateB[n];
      gl[wave * 2 + 0] = sigmoidf_(a0 + gb);
      gl[wave * 2 + 1] = sigmoidf_(a1 + gb);
    }
  }
  __syncthreads();
  // main: h[b][o] for o = tid
  float acc[B_] = {0,0,0,0,0,0,0,0};
  const float4* wp = (const float4*)(fcW + (size_t)n * D_ * D_ + (size_t)tid * D_);
  for (int d4 = 0; d4 < 64; d4++){
    float4 w = wp[d4];
    #pragma unroll
    for (int b = 0; b < B_; b++) acc[b] += dot4f(w, xs4[b * 64 + d4]);
  }
  float fb = fcB[(size_t)n * D_ + tid];
  #pragma unroll
  for (int b = 0; b < B_; b++){
    float s = gelu_exact(acc[b] + fb) * gl[b] * wl[b];
    states[((size_t)(t * K_ + k) * B_ + b) * D_ + tid] = s;
  }
}

// K5 (rewritten): edge pass over per-edge chunks. One block per chunk
// (grid-stride). A chunk = one edge e at up to 2 time steps {t0,t1}.
// connW[e] and fcW[dst] are each streamed ONCE per chunk and amortized
// over nc*B = up to 16 input vectors (2x arithmetic intensity vs item-per-block).
__global__ __launch_bounds__(256) void k_edge3(const float* __restrict__ states,
    const float* __restrict__ connW, const float* __restrict__ fcW,
    const float* __restrict__ fcB, const float* __restrict__ gateW,
    const float* __restrict__ gateB, const int* __restrict__ esrc,
    const int* __restrict__ edst, const int* __restrict__ pos,
    const int* __restrict__ ccount, const unsigned int* __restrict__ chunks,
    float* __restrict__ nxt)
{
  __shared__ float xs[2 * B_ * D_];   // staged states, chunk-major [c][b][d]
  __shared__ float sg[2 * B_ * D_];   // sig              [c][b][o]
  __shared__ float gl[16];            // gate             [c*8 + b]
  int nch = *ccount;
  int tid = threadIdx.x;
  float4* xs4 = (float4*)xs;
  float4* sg4 = (float4*)sg;
  for (int it = blockIdx.x; it < nch; it += gridDim.x){
    unsigned int pk = chunks[it];
    int e  = (int)(pk & 0xFFFFu);
    int t0 = (int)((pk >> 16) & 0xFFu);
    int t1 = (int)((pk >> 24) & 0xFFu);
    int nc = (t1 == 0xFF) ? 1 : 2;
    int src = esrc[e], dst = edst[e];
    int ks0 = pos[t0 * N_ + src], kd0 = pos[t0 * N_ + dst];
    // stage states for the chunk
    {
      const float4* s0 = (const float4*)(states + (size_t)(t0 * K_ + ks0) * B_ * D_);
      xs4[tid] = s0[tid]; xs4[tid + 256] = s0[tid + 256];
      if (nc == 2){
        int ks1 = pos[t1 * N_ + src];
        const float4* s1 = (const float4*)(states + (size_t)(t1 * K_ + ks1) * B_ * D_);
        xs4[tid + 512] = s1[tid]; xs4[tid + 768] = s1[tid + 256];
      }
    }
    __syncthreads();
    // GEMM1: sig[c][b][o=tid] = states[c][b] . connW[e][o]
    {
      const float4* wp = (const float4*)(connW + (size_t)e * D_ * D_ + (size_t)tid * D_);
      if (nc == 2){
        float a0[B_] = {0,0,0,0,0,0,0,0};
        float a1[B_] = {0,0,0,0,0,0,0,0};
        #pragma unroll 16
        for (int d4 = 0; d4 < 64; d4++){
          float4 w = wp[d4];
          #pragma unroll
          for (int b = 0; b < B_; b++){
            a0[b] += dot4f(w, xs4[b * 64 + d4]);
            a1[b] += dot4f(w, xs4[512 + b * 64 + d4]);
          }
        }
        #pragma unroll
        for (int b = 0; b < B_; b++){
          sg[b * D_ + tid] = a0[b];
          sg[2048 + b * D_ + tid] = a1[b];
        }
      } else {
        float a0[B_] = {0,0,0,0,0,0,0,0};
        #pragma unroll 16
        for (int d4 = 0; d4 < 64; d4++){
          float4 w = wp[d4];
          #pragma unroll
          for (int b = 0; b < B_; b++) a0[b] += dot4f(w, xs4[b * 64 + d4]);
        }
        #pragma unroll
        for (int b = 0; b < B_; b++) sg[b * D_ + tid] = a0[b];
      }
    }
    __syncthreads();
    // gates: gl[c*8+b] = sigmoid(sig[c][b] . gateW[dst] + gateB[dst])
    {
      int wv = tid >> 6, ln = tid & 63;
      float4 gw = ((const float4*)(gateW + (size_t)dst * D_))[ln];
      float gb = gateB[dst];
      for (int p = wv; p < 8 * nc; p += 4){
        float a = dot4f(gw, sg4[(p >> 3) * 512 + (p & 7) * 64 + ln]);
        for (int s2 = 1; s2 < 64; s2 <<= 1) a += __shfl_xor(a, s2, 64);
        if (ln == 0) gl[p] = sigmoidf_(a + gb);
      }
    }
    __syncthreads();
    // GEMM2: hh[c][b][o=tid] = sig[c][b] . fcW[dst][o]; act -> atomic into nxt
    {
      const float4* wq = (const float4*)(fcW + (size_t)dst * D_ * D_ + (size_t)tid * D_);
      float fb = fcB[(size_t)dst * D_ + tid];
      if (nc == 2){
        float b0[B_] = {0,0,0,0,0,0,0,0};
        float b1[B_] = {0,0,0,0,0,0,0,0};
        #pragma unroll 16
        for (int d4 = 0; d4 < 64; d4++){
          float4 w = wq[d4];
          #pragma unroll
          for (int b = 0; b < B_; b++){
            b0[b] += dot4f(w, sg4[b * 64 + d4]);
            b1[b] += dot4f(w, sg4[512 + b * 64 + d4]);
          }
        }
        int kd1 = pos[t1 * N_ + dst];
        float* nx0 = nxt + (size_t)(t0 * K_ + kd0) * B_ * D_;
        float* nx1 = nxt + (size_t)(t1 * K_ + kd1) * B_ * D_;
        #pragma unroll
        for (int b = 0; b < B_; b++){
          atomicAdd(&nx0[b * D_ + tid], gelu_exact(b0[b] + fb) * gl[b]);
          atomicAdd(&nx1[b * D_ + tid], gelu_exact(b1[b] + fb) * gl[8 + b]);
        }
      } else {
        float b0[B_] = {0,0,0,0,0,0,0,0};
        #pragma unroll 16
        for (int d4 = 0; d4 < 64; d4++){
          float4 w = wq[d4];
          #pragma unroll
          for (int b = 0; b < B_; b++) b0[b] += dot4f(w, sg4[b * 64 + d4]);
        }
        float* nx0 = nxt + (size_t)(t0 * K_ + kd0) * B_ * D_;
        #pragma unroll
        for (int b = 0; b < B_; b++)
          atomicAdd(&nx0[b * D_ + tid], gelu_exact(b0[b] + fb) * gl[b]);
      }
    }
    __syncthreads();   // protect xs/sg before next grid-stride iteration
  }
}

// K6: combine (mean over k of states+0.5*nxt) + LayerNorm -> normed[row=b*S+t][d]
__global__ __launch_bounds__(256) void k_ln(const float* __restrict__ states,
    const float* __restrict__ nxt, const float* __restrict__ lng,
    const float* __restrict__ lnb, float* __restrict__ normed)
{
  int row = blockIdx.x;           // b*S + t
  int b = row >> 5, t = row & 31;
  int d = threadIdx.x;
  float v = 0.0f;
  for (int k = 0; k < K_; k++){
    size_t idx = ((size_t)(t * K_ + k) * B_ + b) * D_ + d;
    v += states[idx] + 0.5f * nxt[idx];
  }
  v /= 51.0f;
  __shared__ float red[256];
  red[d] = v; __syncthreads();
  for (int s = 128; s > 0; s >>= 1){ if (d < s) red[d] += red[d + s]; __syncthreads(); }
  float mu = red[0] * (1.0f / 256.0f);
  __syncthreads();
  float c = v - mu;
  red[d] = c * c; __syncthreads();
  for (int s = 128; s > 0; s >>= 1){ if (d < s) red[d] += red[d + s]; __syncthreads(); }
  float var = red[0] * (1.0f / 256.0f);
  normed[(size_t)row * D_ + d] = c * rsqrtf(var + 1e-5f) * lng[d] + lnb[d];
}

// K7: tiled FP32 GEMM. out[r][v] = dot(normed[r], outW[v]) + outB[v].
// Block tile: 64 rows x 128 cols, K-chunks of 64 staged TRANSPOSED into LDS.
__global__ __launch_bounds__(256) void k_logits(const float* __restrict__ normed,
    const float* __restrict__ outW, const float* __restrict__ outB,
    float* __restrict__ out)
{
  __shared__ float Ws[64][132];   // 33792 B
  __shared__ float Xs[64][68];    // 17408 B
  int tid = threadIdx.x;
  int vbase = blockIdx.x * 128;
  int rbase = blockIdx.y * 64;
  int cg = tid & 31;              // 4 cols: vbase + cg*4 + j
  int rg = tid >> 5;              // 8 rows: rbase + rg*8 + i
  float acc[8][4];
  #pragma unroll
  for (int i = 0; i < 8; i++)
    #pragma unroll
    for (int j = 0; j < 4; j++) acc[i][j] = 0.0f;

  for (int kb = 0; kb < 4; kb++){           // k-chunk = [kb*64, kb*64+64)
    if (kb) __syncthreads();                // protect prev-chunk reads
    // stage W chunk transposed: 128 rows(v) x 16 float4(k) = 2048 quads, 8/thread
    #pragma unroll
    for (int i = 0; i < 8; i++){
      int idx = tid + i * 256;
      int v = idx >> 4, kq = idx & 15;
      int gv = vbase + v;
      float4 w = make_float4(0.0f, 0.0f, 0.0f, 0.0f);
      if (gv < V_) w = ((const float4*)(outW + (size_t)gv * D_))[kb * 16 + kq];
      Ws[kq * 4 + 0][v] = w.x;
      Ws[kq * 4 + 1][v] = w.y;
      Ws[kq * 4 + 2][v] = w.z;
      Ws[kq * 4 + 3][v] = w.w;
    }
    // stage X chunk transposed: 64 rows x 16 quads = 1024 quads, 4/thread
    #pragma unroll
    for (int i = 0; i < 4; i++){
      int idx = tid + i * 256;
      int r = idx >> 4, kq = idx & 15;
      float4 x = ((const float4*)(normed + (size_t)(rbase + r) * D_))[kb * 16 + kq];
      Xs[kq * 4 + 0][r] = x.x;
      Xs[kq * 4 + 1][r] = x.y;
      Xs[kq * 4 + 2][r] = x.z;
      Xs[kq * 4 + 3][r] = x.w;
    }
    __syncthreads();
    // outer-product inner loop: per k, 3 ds_read_b128 + 32 v_fma
    #pragma unroll 4
    for (int k = 0; k < 64; k++){
      float4 wv = *(const float4*)&Ws[k][cg * 4];
      float4 x0 = *(const float4*)&Xs[k][rg * 8];
      float4 x1 = *(const float4*)&Xs[k][rg * 8 + 4];
      float xr[8] = {x0.x, x0.y, x0.z, x0.w, x1.x, x1.y, x1.z, x1.w};
      float wc[4] = {wv.x, wv.y, wv.z, wv.w};
      #pragma unroll
      for (int i = 0; i < 8; i++)
        #pragma unroll
        for (int j = 0; j < 4; j++)
          acc[i][j] = fmaf(xr[i], wc[j], acc[i][j]);
    }
  }
  // epilogue: scalar stores (V odd -> no aligned vector stores)
  #pragma unroll
  for (int j = 0; j < 4; j++){
    int gc = vbase + cg * 4 + j;
    if (gc < V_){
      float ob = outB[gc];
      #pragma unroll
      for (int i = 0; i < 8; i++)
        out[(size_t)(rbase + rg * 8 + i) * V_ + gc] = acc[i][j] + ob;
    }
  }
}

extern "C" void kernel_launch(void* const* d_in, const int* in_sizes, int n_in,
                              void* d_out, int out_size, void* d_ws, size_t ws_size,
                              hipStream_t stream)
{
  const int*   ids    = (const int*)d_in[0];
  const float* embed  = (const float*)d_in[1];
  const float* pose   = (const float*)d_in[2];
  const float* rW     = (const float*)d_in[3];
  const float* rb     = (const float*)d_in[4];
  const float* fcW    = (const float*)d_in[5];
  const float* fcB    = (const float*)d_in[6];
  const float* gateW  = (const float*)d_in[7];
  const float* gateB  = (const float*)d_in[8];
  const float* connW  = (const float*)d_in[9];
  const float* lng    = (const float*)d_in[10];
  const float* lnb    = (const float*)d_in[11];
  const float* outW   = (const float*)d_in[12];
  const float* outB   = (const float*)d_in[13];
  const int*   esrc   = (const int*)d_in[14];
  const int*   edst   = (const int*)d_in[15];
  int E = in_sizes[14];
  float* out = (float*)d_out;

  char* ws = (char*)d_ws;
  float* xt     = (float*)(ws + 0);          // 256 KB
  float* scores = (float*)(ws + 262144);     // 256 KB (dead after k_topk)
  // alias chunk worklist into the dead scores region (worst case E*16*4 B = 65 KB):
  unsigned int* chunks = (unsigned int*)(ws + 262144);
  float* wbuf   = (float*)(ws + 524288);     // 52 KB
  int*   active = (int*)  (ws + 589824);     // 6.5 KB
  int*   ccount = (int*)  (ws + 596992);     // 4 B (slack before member)
  int*   member = (int*)  (ws + 598016);     // 32 KB
  int*   pos    = (int*)  (ws + 630784);     // 32 KB
  float* states = (float*)(ws + 663552);     // 13.37 MB
  float* nxt    = (float*)(ws + 14032896);   // 13.37 MB
  float* normed = (float*)(ws + 27402240);   // 256 KB

  hipMemsetAsync(nxt, 0, (size_t)3342336 * 4, stream);

  k_embed  <<<dim3(S_ * B_), 256, 0, stream>>>(ids, embed, pose, xt);
  k_router <<<dim3(S_ * B_), 256, 0, stream>>>(xt, rW, rb, scores);
  k_topk   <<<dim3(S_ * B_), 256, 0, stream>>>(scores, wbuf, active, member, pos);
  hipMemsetAsync(ccount, 0, 4, stream);      // after k_topk: scores region now dead
  k_chunks <<<dim3((E + 255) / 256), 256, 0, stream>>>(esrc, edst, member, E, ccount, chunks);
  k_hop0   <<<dim3(K_, S_), 256, 0, stream>>>(xt, fcW, fcB, gateW, gateB, wbuf, active, states);
  k_edge3  <<<dim3(1024), 256, 0, stream>>>(states, connW, fcW, fcB, gateW, gateB,
                                            esrc, edst, pos, ccount, chunks, nxt);
  k_ln     <<<dim3(B_ * S_), 256, 0, stream>>>(states, nxt, lng, lnb, normed);
  k_logits <<<dim3((V_ + 127) / 128, 4), 256, 0, stream>>>(normed, outW, outB, out);
}

// Round 3
// 709.598 us; speedup vs baseline: 1.4822x; 1.1215x over previous
//
#include <hip/hip_runtime.h>
#include <math.h>

#define B_ 8
#define S_ 32
#define D_ 256
#define N_ 256
#define K_ 51
#define V_ 50257

__device__ __forceinline__ float dot4f(float4 a, float4 b){
  return a.x*b.x + a.y*b.y + a.z*b.z + a.w*b.w;
}
__device__ __forceinline__ float gelu_exact(float x){
  return 0.5f * x * (1.0f + erff(x * 0.70710678118654752440f));
}
__device__ __forceinline__ float sigmoidf_(float x){
  return 1.0f / (1.0f + expf(-x));
}

// K1: xt[t*B+b][d] = embed[ids[b,t]][d] + pos_embed[t][d]
__global__ __launch_bounds__(256) void k_embed(const int* __restrict__ ids,
    const float* __restrict__ embed, const float* __restrict__ pose,
    float* __restrict__ xt)
{
  int bx = blockIdx.x;            // t*8 + b
  int t = bx >> 3, b = bx & 7;
  int d = threadIdx.x;
  int id = ids[b * S_ + t];
  xt[(size_t)bx * D_ + d] = embed[(size_t)id * D_ + d] + pose[(size_t)t * D_ + d];
}

// K2: scores[t*B+b][n] = dot(xt[t,b], router_W[n]) + router_b[n]
__global__ __launch_bounds__(256) void k_router(const float* __restrict__ xt,
    const float* __restrict__ rW, const float* __restrict__ rb,
    float* __restrict__ scores)
{
  int bx = blockIdx.x;            // t*8 + b
  int tid = threadIdx.x;
  __shared__ float4 xs4[64];
  if (tid < 64) xs4[tid] = ((const float4*)(xt + (size_t)bx * D_))[tid];
  __syncthreads();
  float acc = rb[tid];
  const float4* wp = (const float4*)(rW + (size_t)tid * D_);
  for (int d4 = 0; d4 < 64; d4++){
    float4 w = wp[d4]; float4 x = xs4[d4];
    acc += dot4f(w, x);
  }
  scores[(size_t)bx * N_ + tid] = acc;
}

// K3: per (t,b): full bitonic sort desc (tie: low idx first), softmax over top-K,
// and for b==0 build active/member/pos for step t.
__global__ __launch_bounds__(256) void k_topk(const float* __restrict__ scores,
    float* __restrict__ wbuf, int* __restrict__ active,
    int* __restrict__ member, int* __restrict__ pos)
{
  int bx = blockIdx.x;            // t*8 + b
  int t = bx >> 3, b = bx & 7;
  int tid = threadIdx.x;
  __shared__ float sv[256];
  __shared__ int   si[256];
  __shared__ float ex[K_];
  __shared__ float exsum;
  sv[tid] = scores[(size_t)bx * N_ + tid];
  si[tid] = tid;
  for (int kk = 2; kk <= 256; kk <<= 1){
    for (int j = kk >> 1; j > 0; j >>= 1){
      __syncthreads();
      int ixj = tid ^ j;
      if (ixj > tid){
        float va = sv[tid], vb = sv[ixj];
        int   ia = si[tid], ib = si[ixj];
        bool before = (va > vb) || (va == vb && ia < ib);
        bool up = ((tid & kk) == 0);
        if (up != before){
          sv[tid] = vb; sv[ixj] = va;
          si[tid] = ib; si[ixj] = ia;
        }
      }
    }
  }
  __syncthreads();
  float vmax = sv[0];
  if (tid < K_) ex[tid] = expf(sv[tid] - vmax);
  __syncthreads();
  if (tid == 0){
    float s = 0.0f;
    for (int k = 0; k < K_; k++) s += ex[k];
    exsum = s;
  }
  __syncthreads();
  if (tid < K_) wbuf[(size_t)bx * K_ + tid] = ex[tid] / exsum;
  if (b == 0){
    member[t * N_ + tid] = 0;
    pos[t * N_ + tid] = 0;
    __syncthreads();               // uniform branch within block
    if (tid < K_){
      int nn = si[tid];
      active[t * K_ + tid] = nn;
      member[t * N_ + nn] = 1;
      pos[t * N_ + nn] = tid;
    }
  }
}

// K3b: thread-per-edge. Emit chunks of up to 2 t's: e | t0<<16 | t1<<24
// (t1 == 0xFF means single-t chunk).
__global__ __launch_bounds__(256) void k_chunks(const int* __restrict__ esrc,
    const int* __restrict__ edst, const int* __restrict__ member,
    int E, int* __restrict__ ccount, unsigned int* __restrict__ chunks)
{
  int e = blockIdx.x * 256 + threadIdx.x;
  if (e >= E) return;
  int src = esrc[e], dst = edst[e];
  unsigned int mask = 0;
  for (int t = 0; t < S_; t++)
    if (member[t * N_ + src] && member[t * N_ + dst]) mask |= (1u << t);
  while (mask){
    int t0 = __ffs(mask) - 1; mask &= mask - 1;
    unsigned int t1 = 0xFFu;
    if (mask){ t1 = (unsigned int)(__ffs(mask) - 1); mask &= mask - 1; }
    int ci = atomicAdd(ccount, 1);
    chunks[ci] = (unsigned int)e | ((unsigned int)t0 << 16) | (t1 << 24);
  }
}

// K3c: thread-per-neuron. Emit chunks of up to 4 t's where neuron is active:
// n | t0<<8 | t1<<14 | t2<<20 | t3<<26 (sentinel 0x3F).
__global__ __launch_bounds__(256) void k_nchunks(const int* __restrict__ member,
    int* __restrict__ ncount, unsigned int* __restrict__ nchunks)
{
  int n = threadIdx.x;            // single block of 256
  unsigned int mask = 0;
  for (int t = 0; t < S_; t++)
    if (member[t * N_ + n]) mask |= (1u << t);
  while (mask){
    unsigned int t0 = (unsigned int)(__ffs(mask) - 1); mask &= mask - 1;
    unsigned int t1 = 0x3Fu, t2 = 0x3Fu, t3 = 0x3Fu;
    if (mask){ t1 = (unsigned int)(__ffs(mask) - 1); mask &= mask - 1; }
    if (mask){ t2 = (unsigned int)(__ffs(mask) - 1); mask &= mask - 1; }
    if (mask){ t3 = (unsigned int)(__ffs(mask) - 1); mask &= mask - 1; }
    int ci = atomicAdd(ncount, 1);
    nchunks[ci] = (unsigned int)n | (t0 << 8) | (t1 << 14) | (t2 << 20) | (t3 << 26);
  }
}

// K4 (rewritten): hop0 over neuron chunks. Block per chunk (grid-stride):
// one neuron n at up to 4 timesteps. M = nt*8 rows, N = 256 outs, K = 256.
// fcW[n] staged coalesced+transposed into LDS in K-chunks of 32; outer-product
// inner loop (3 LDS reads : 32 FMA). Also zero-inits nxt (replaces memset).
__global__ __launch_bounds__(256) void k_hop0(const float* __restrict__ xt,
    const float* __restrict__ fcW, const float* __restrict__ fcB,
    const float* __restrict__ gateW, const float* __restrict__ gateB,
    const float* __restrict__ wbuf, const int* __restrict__ pos,
    const int* __restrict__ ncount, const unsigned int* __restrict__ nchunks,
    float* __restrict__ states, float* __restrict__ nxt)
{
  __shared__ float XT[256][36];   // X transposed: XT[k][m], m = ti*8+b
  __shared__ float Ws[32][260];   // W chunk transposed: Ws[kk][o]
  __shared__ float gl[32];        // gates
  int nch = *ncount;
  int tid = threadIdx.x;
  int cg = tid & 63;              // o = cg*4 .. +3
  int rg = tid >> 6;              // ti = rg, b = 0..7
  for (int it = blockIdx.x; it < nch; it += gridDim.x){
    __syncthreads();              // protect LDS from previous iteration
    unsigned int pk = nchunks[it];
    int n = (int)(pk & 255u);
    int nt = 1 + (((pk >> 14) & 63u) != 63u) + (((pk >> 20) & 63u) != 63u)
               + (((pk >> 26) & 63u) != 63u);
    // stage XT: 32 rows x 64 quads, 8 quads/thread; zero rows for ti >= nt
    #pragma unroll
    for (int i = 0; i < 8; i++){
      int idx = tid + i * 256;
      int r = idx & 31, kq = idx >> 5;
      int ti = r >> 3, b = r & 7;
      float4 v = make_float4(0.0f, 0.0f, 0.0f, 0.0f);
      if (ti < nt){
        int t = (int)((pk >> (8 + 6 * ti)) & 63u);
        v = ((const float4*)(xt + (size_t)(t * 8 + b) * D_))[kq];
      }
      XT[kq * 4 + 0][r] = v.x;
      XT[kq * 4 + 1][r] = v.y;
      XT[kq * 4 + 2][r] = v.z;
      XT[kq * 4 + 3][r] = v.w;
    }
    // gates: wave rg computes gl[rg*8+b] for its timestep (reads global xt, L2-hot)
    if (rg < nt){
      int t = (int)((pk >> (8 + 6 * rg)) & 63u);
      float4 gw = ((const float4*)(gateW + (size_t)n * D_))[cg];
      float gb = gateB[n];
      for (int b = 0; b < 8; b++){
        float a = dot4f(gw, ((const float4*)(xt + (size_t)(t * 8 + b) * D_))[cg]);
        for (int s2 = 1; s2 < 64; s2 <<= 1) a += __shfl_xor(a, s2, 64);
        if (cg == 0) gl[rg * 8 + b] = sigmoidf_(a + gb);
      }
    }
    __syncthreads();
    // main GEMM: acc[b][j] over K in chunks of 32
    float acc[8][4];
    #pragma unroll
    for (int i = 0; i < 8; i++)
      #pragma unroll
      for (int j = 0; j < 4; j++) acc[i][j] = 0.0f;
    const float4* wsrc = (const float4*)(fcW + (size_t)n * D_ * D_);
    for (int kb = 0; kb < 8; kb++){
      if (kb) __syncthreads();
      // stage Ws[32][260]: 2048 quads, 8/thread (o = idx>>3, q = idx&7)
      #pragma unroll
      for (int i = 0; i < 8; i++){
        int idx = tid + i * 256;
        int o = idx >> 3, q = idx & 7;
        float4 w = wsrc[(size_t)o * 64 + kb * 8 + q];
        Ws[q * 4 + 0][o] = w.x;
        Ws[q * 4 + 1][o] = w.y;
        Ws[q * 4 + 2][o] = w.z;
        Ws[q * 4 + 3][o] = w.w;
      }
      __syncthreads();
      #pragma unroll 8
      for (int kk = 0; kk < 32; kk++){
        float4 w = *(const float4*)&Ws[kk][cg * 4];
        float4 xa = *(const float4*)&XT[kb * 32 + kk][rg * 8];
        float4 xb = *(const float4*)&XT[kb * 32 + kk][rg * 8 + 4];
        float xr[8] = {xa.x, xa.y, xa.z, xa.w, xb.x, xb.y, xb.z, xb.w};
        float wc[4] = {w.x, w.y, w.z, w.w};
        #pragma unroll
        for (int i = 0; i < 8; i++)
          #pragma unroll
          for (int j = 0; j < 4; j++)
            acc[i][j] = fmaf(xr[i], wc[j], acc[i][j]);
      }
    }
    // epilogue: thread owns (ti=rg, b=0..7, o=cg*4..+3)
    if (rg < nt){
      int t = (int)((pk >> (8 + 6 * rg)) & 63u);
      int kpos = pos[t * N_ + n];
      float4 fb = ((const float4*)(fcB + (size_t)n * D_))[cg];
      #pragma unroll
      for (int b = 0; b < 8; b++){
        float w_ = wbuf[(size_t)(t * 8 + b) * K_ + kpos];
        float g_ = gl[rg * 8 + b];
        float4 o4;
        o4.x = gelu_exact(acc[b][0] + fb.x) * g_ * w_;
        o4.y = gelu_exact(acc[b][1] + fb.y) * g_ * w_;
        o4.z = gelu_exact(acc[b][2] + fb.z) * g_ * w_;
        o4.w = gelu_exact(acc[b][3] + fb.w) * g_ * w_;
        size_t base = ((size_t)(t * K_ + kpos) * 8 + b) * D_ + cg * 4;
        *(float4*)(states + base) = o4;
        *(float4*)(nxt + base) = make_float4(0.0f, 0.0f, 0.0f, 0.0f);  // fused zero-init
      }
    }
  }
}

// K5 (rewritten): edge pass, LDS-tiled. Block per chunk (e, <=2 t's).
// GEMM1: sig = states(16x256) . connW[e]^T ; GEMM2: hh = sig . fcW[dst]^T.
// Weights staged coalesced+transposed in K-chunks of 32; sig re-staged
// transposed between GEMMs.
__global__ __launch_bounds__(256) void k_edge3(const float* __restrict__ states,
    const float* __restrict__ connW, const float* __restrict__ fcW,
    const float* __restrict__ fcB, const float* __restrict__ gateW,
    const float* __restrict__ gateB, const int* __restrict__ esrc,
    const int* __restrict__ edst, const int* __restrict__ pos,
    const int* __restrict__ ccount, const unsigned int* __restrict__ chunks,
    float* __restrict__ nxt)
{
  __shared__ float XT[256][20];   // transposed operand: XT[k][m]
  __shared__ float Ws[32][260];   // W chunk transposed: Ws[kk][o]
  __shared__ float sgl[16][260];  // sig linear [m][o]
  __shared__ float gl[16];
  int nch = *ccount;
  int tid = threadIdx.x;
  int cg = tid & 63;              // o = cg*4 .. +3
  int rg = tid >> 6;              // m = rg*4 .. +3
  for (int it = blockIdx.x; it < nch; it += gridDim.x){
    __syncthreads();              // protect LDS from previous iteration
    unsigned int pk = chunks[it];
    int e  = (int)(pk & 0xFFFFu);
    int t0 = (int)((pk >> 16) & 0xFFu);
    int t1 = (int)((pk >> 24) & 0xFFu);
    int nc = (t1 == 0xFF) ? 1 : 2;
    int src = esrc[e], dst = edst[e];
    int ks0 = pos[t0 * N_ + src], kd0 = pos[t0 * N_ + dst];
    int ks1 = (nc == 2) ? pos[t1 * N_ + src] : 0;
    int kd1 = (nc == 2) ? pos[t1 * N_ + dst] : 0;
    // stage XT from states rows (m = c*8+b): 16 rows x 64 quads, 4/thread
    #pragma unroll
    for (int i = 0; i < 4; i++){
      int idx = tid + i * 256;
      int r = idx & 15, kq = idx >> 4;
      int c = r >> 3, b = r & 7;
      float4 v = make_float4(0.0f, 0.0f, 0.0f, 0.0f);
      if (c < nc){
        int t = c ? t1 : t0;
        int ks = c ? ks1 : ks0;
        v = ((const float4*)(states + ((size_t)(t * K_ + ks) * 8 + b) * D_))[kq];
      }
      XT[kq * 4 + 0][r] = v.x;
      XT[kq * 4 + 1][r] = v.y;
      XT[kq * 4 + 2][r] = v.z;
      XT[kq * 4 + 3][r] = v.w;
    }
    __syncthreads();
    // GEMM1: connW[e]
    float acc[4][4];
    #pragma unroll
    for (int i = 0; i < 4; i++)
      #pragma unroll
      for (int j = 0; j < 4; j++) acc[i][j] = 0.0f;
    {
      const float4* wsrc = (const float4*)(connW + (size_t)e * D_ * D_);
      for (int kb = 0; kb < 8; kb++){
        if (kb) __syncthreads();
        #pragma unroll
        for (int i = 0; i < 8; i++){
          int idx = tid + i * 256;
          int o = idx >> 3, q = idx & 7;
          float4 w = wsrc[(size_t)o * 64 + kb * 8 + q];
          Ws[q * 4 + 0][o] = w.x;
          Ws[q * 4 + 1][o] = w.y;
          Ws[q * 4 + 2][o] = w.z;
          Ws[q * 4 + 3][o] = w.w;
        }
        __syncthreads();
        #pragma unroll 8
        for (int kk = 0; kk < 32; kk++){
          float4 w = *(const float4*)&Ws[kk][cg * 4];
          float4 x = *(const float4*)&XT[kb * 32 + kk][rg * 4];
          float xr[4] = {x.x, x.y, x.z, x.w};
          float wc[4] = {w.x, w.y, w.z, w.w};
          #pragma unroll
          for (int i = 0; i < 4; i++)
            #pragma unroll
            for (int j = 0; j < 4; j++)
              acc[i][j] = fmaf(xr[i], wc[j], acc[i][j]);
        }
      }
    }
    // write sig linear
    #pragma unroll
    for (int i = 0; i < 4; i++)
      *(float4*)&sgl[rg * 4 + i][cg * 4] = make_float4(acc[i][0], acc[i][1], acc[i][2], acc[i][3]);
    __syncthreads();
    // transpose sig -> XT (reuse buffer)
    #pragma unroll
    for (int i = 0; i < 4; i++){
      int idx = tid + i * 256;
      int r = idx & 15, kq = idx >> 4;
      float4 v = *(const float4*)&sgl[r][kq * 4];
      XT[kq * 4 + 0][r] = v.x;
      XT[kq * 4 + 1][r] = v.y;
      XT[kq * 4 + 2][r] = v.z;
      XT[kq * 4 + 3][r] = v.w;
    }
    // gates from sig linear
    {
      float4 gw = ((const float4*)(gateW + (size_t)dst * D_))[cg];
      float gb = gateB[dst];
      for (int p = rg; p < 8 * nc; p += 4){
        float a = dot4f(gw, *(const float4*)&sgl[p][cg * 4]);
        for (int s2 = 1; s2 < 64; s2 <<= 1) a += __shfl_xor(a, s2, 64);
        if (cg == 0) gl[p] = sigmoidf_(a + gb);
      }
    }
    // GEMM2: fcW[dst]  (first Ws staging needs transpose+gates done -> sync)
    __syncthreads();
    #pragma unroll
    for (int i = 0; i < 4; i++)
      #pragma unroll
      for (int j = 0; j < 4; j++) acc[i][j] = 0.0f;
    {
      const float4* wsrc = (const float4*)(fcW + (size_t)dst * D_ * D_);
      for (int kb = 0; kb < 8; kb++){
        if (kb) __syncthreads();
        #pragma unroll
        for (int i = 0; i < 8; i++){
          int idx = tid + i * 256;
          int o = idx >> 3, q = idx & 7;
          float4 w = wsrc[(size_t)o * 64 + kb * 8 + q];
          Ws[q * 4 + 0][o] = w.x;
          Ws[q * 4 + 1][o] = w.y;
          Ws[q * 4 + 2][o] = w.z;
          Ws[q * 4 + 3][o] = w.w;
        }
        __syncthreads();
        #pragma unroll 8
        for (int kk = 0; kk < 32; kk++){
          float4 w = *(const float4*)&Ws[kk][cg * 4];
          float4 x = *(const float4*)&XT[kb * 32 + kk][rg * 4];
          float xr[4] = {x.x, x.y, x.z, x.w};
          float wc[4] = {w.x, w.y, w.z, w.w};
          #pragma unroll
          for (int i = 0; i < 4; i++)
            #pragma unroll
            for (int j = 0; j < 4; j++)
              acc[i][j] = fmaf(xr[i], wc[j], acc[i][j]);
        }
      }
    }
    // epilogue: atomics into nxt
    float4 fb = ((const float4*)(fcB + (size_t)dst * D_))[cg];
    #pragma unroll
    for (int i = 0; i < 4; i++){
      int m = rg * 4 + i;
      int c = m >> 3, b = m & 7;
      if (c < nc){
        int t = c ? t1 : t0;
        int kd = c ? kd1 : kd0;
        float g_ = gl[m];
        float* nx = nxt + ((size_t)(t * K_ + kd) * 8 + b) * D_ + cg * 4;
        atomicAdd(&nx[0], gelu_exact(acc[i][0] + fb.x) * g_);
        atomicAdd(&nx[1], gelu_exact(acc[i][1] + fb.y) * g_);
        atomicAdd(&nx[2], gelu_exact(acc[i][2] + fb.z) * g_);
        atomicAdd(&nx[3], gelu_exact(acc[i][3] + fb.w) * g_);
      }
    }
  }
}

// K6: combine (mean over k of states+0.5*nxt) + LayerNorm -> normed[row=b*S+t][d]
__global__ __launch_bounds__(256) void k_ln(const float* __restrict__ states,
    const float* __restrict__ nxt, const float* __restrict__ lng,
    const float* __restrict__ lnb, float* __restrict__ normed)
{
  int row = blockIdx.x;           // b*S + t
  int b = row >> 5, t = row & 31;
  int d = threadIdx.x;
  float v = 0.0f;
  for (int k = 0; k < K_; k++){
    size_t idx = ((size_t)(t * K_ + k) * B_ + b) * D_ + d;
    v += states[idx] + 0.5f * nxt[idx];
  }
  v /= 51.0f;
  __shared__ float red[256];
  red[d] = v; __syncthreads();
  for (int s = 128; s > 0; s >>= 1){ if (d < s) red[d] += red[d + s]; __syncthreads(); }
  float mu = red[0] * (1.0f / 256.0f);
  __syncthreads();
  float c = v - mu;
  red[d] = c * c; __syncthreads();
  for (int s = 128; s > 0; s >>= 1){ if (d < s) red[d] += red[d + s]; __syncthreads(); }
  float var = red[0] * (1.0f / 256.0f);
  normed[(size_t)row * D_ + d] = c * rsqrtf(var + 1e-5f) * lng[d] + lnb[d];
}

// K7: tiled FP32 GEMM. out[r][v] = dot(normed[r], outW[v]) + outB[v].
__global__ __launch_bounds__(256) void k_logits(const float* __restrict__ normed,
    const float* __restrict__ outW, const float* __restrict__ outB,
    float* __restrict__ out)
{
  __shared__ float Ws[64][132];   // 33792 B
  __shared__ float Xs[64][68];    // 17408 B
  int tid = threadIdx.x;
  int vbase = blockIdx.x * 128;
  int rbase = blockIdx.y * 64;
  int cg = tid & 31;              // 4 cols: vbase + cg*4 + j
  int rg = tid >> 5;              // 8 rows: rbase + rg*8 + i
  float acc[8][4];
  #pragma unroll
  for (int i = 0; i < 8; i++)
    #pragma unroll
    for (int j = 0; j < 4; j++) acc[i][j] = 0.0f;

  for (int kb = 0; kb < 4; kb++){
    if (kb) __syncthreads();
    #pragma unroll
    for (int i = 0; i < 8; i++){
      int idx = tid + i * 256;
      int v = idx >> 4, kq = idx & 15;
      int gv = vbase + v;
      float4 w = make_float4(0.0f, 0.0f, 0.0f, 0.0f);
      if (gv < V_) w = ((const float4*)(outW + (size_t)gv * D_))[kb * 16 + kq];
      Ws[kq * 4 + 0][v] = w.x;
      Ws[kq * 4 + 1][v] = w.y;
      Ws[kq * 4 + 2][v] = w.z;
      Ws[kq * 4 + 3][v] = w.w;
    }
    #pragma unroll
    for (int i = 0; i < 4; i++){
      int idx = tid + i * 256;
      int r = idx >> 4, kq = idx & 15;
      float4 x = ((const float4*)(normed + (size_t)(rbase + r) * D_))[kb * 16 + kq];
      Xs[kq * 4 + 0][r] = x.x;
      Xs[kq * 4 + 1][r] = x.y;
      Xs[kq * 4 + 2][r] = x.z;
      Xs[kq * 4 + 3][r] = x.w;
    }
    __syncthreads();
    #pragma unroll 4
    for (int k = 0; k < 64; k++){
      float4 wv = *(const float4*)&Ws[k][cg * 4];
      float4 x0 = *(const float4*)&Xs[k][rg * 8];
      float4 x1 = *(const float4*)&Xs[k][rg * 8 + 4];
      float xr[8] = {x0.x, x0.y, x0.z, x0.w, x1.x, x1.y, x1.z, x1.w};
      float wc[4] = {wv.x, wv.y, wv.z, wv.w};
      #pragma unroll
      for (int i = 0; i < 8; i++)
        #pragma unroll
        for (int j = 0; j < 4; j++)
          acc[i][j] = fmaf(xr[i], wc[j], acc[i][j]);
    }
  }
  #pragma unroll
  for (int j = 0; j < 4; j++){
    int gc = vbase + cg * 4 + j;
    if (gc < V_){
      float ob = outB[gc];
      #pragma unroll
      for (int i = 0; i < 8; i++)
        out[(size_t)(rbase + rg * 8 + i) * V_ + gc] = acc[i][j] + ob;
    }
  }
}

extern "C" void kernel_launch(void* const* d_in, const int* in_sizes, int n_in,
                              void* d_out, int out_size, void* d_ws, size_t ws_size,
                              hipStream_t stream)
{
  const int*   ids    = (const int*)d_in[0];
  const float* embed  = (const float*)d_in[1];
  const float* pose   = (const float*)d_in[2];
  const float* rW     = (const float*)d_in[3];
  const float* rb     = (const float*)d_in[4];
  const float* fcW    = (const float*)d_in[5];
  const float* fcB    = (const float*)d_in[6];
  const float* gateW  = (const float*)d_in[7];
  const float* gateB  = (const float*)d_in[8];
  const float* connW  = (const float*)d_in[9];
  const float* lng    = (const float*)d_in[10];
  const float* lnb    = (const float*)d_in[11];
  const float* outW   = (const float*)d_in[12];
  const float* outB   = (const float*)d_in[13];
  const int*   esrc   = (const int*)d_in[14];
  const int*   edst   = (const int*)d_in[15];
  int E = in_sizes[14];
  float* out = (float*)d_out;

  char* ws = (char*)d_ws;
  float* xt     = (float*)(ws + 0);          // 256 KB
  float* scores = (float*)(ws + 262144);     // 256 KB (dead after k_topk)
  // alias worklists into the dead scores region:
  unsigned int* chunks  = (unsigned int*)(ws + 262144);   // edge chunks, <= 64 KB
  unsigned int* nchunks = (unsigned int*)(ws + 327680);   // neuron chunks, <= 8 KB
  float* wbuf   = (float*)(ws + 524288);     // 52 KB
  int*   active = (int*)  (ws + 589824);     // 6.5 KB
  int*   ccount = (int*)  (ws + 596992);     // 4 B
  int*   ncount = (int*)  (ws + 596996);     // 4 B
  int*   member = (int*)  (ws + 598016);     // 32 KB
  int*   pos    = (int*)  (ws + 630784);     // 32 KB
  float* states = (float*)(ws + 663552);     // 13.37 MB
  float* nxt    = (float*)(ws + 14032896);   // 13.37 MB (zero-init fused into k_hop0)
  float* normed = (float*)(ws + 27402240);   // 256 KB

  k_embed  <<<dim3(S_ * B_), 256, 0, stream>>>(ids, embed, pose, xt);
  k_router <<<dim3(S_ * B_), 256, 0, stream>>>(xt, rW, rb, scores);
  k_topk   <<<dim3(S_ * B_), 256, 0, stream>>>(scores, wbuf, active, member, pos);
  hipMemsetAsync(ccount, 0, 8, stream);      // ccount + ncount; scores region now dead
  k_chunks <<<dim3((E + 255) / 256), 256, 0, stream>>>(esrc, edst, member, E, ccount, chunks);
  k_nchunks<<<dim3(1), 256, 0, stream>>>(member, ncount, nchunks);
  k_hop0   <<<dim3(512), 256, 0, stream>>>(xt, fcW, fcB, gateW, gateB, wbuf, pos,
                                           ncount, nchunks, states, nxt);
  k_edge3  <<<dim3(1024), 256, 0, stream>>>(states, connW, fcW, fcB, gateW, gateB,
                                            esrc, edst, pos, ccount, chunks, nxt);
  k_ln     <<<dim3(B_ * S_), 256, 0, stream>>>(states, nxt, lng, lnb, normed);
  k_logits <<<dim3((V_ + 127) / 128, 4), 256, 0, stream>>>(normed, outW, outB, out);
}